// Round 7
// baseline (44.779 us; speedup 1.0000x reference)
//
#include <hip/hip_runtime.h>
#include <stdint.h>

// KumaMask: z = clip(Kumaraswamy-rsample stretch, 0, 1)
//   a = softplus(x·Wa + ba); b = softplus(x·Wb + bb)
//   u = jax.random.uniform(key(42)) — threefry2x32 PARTITIONABLE stream
//     (counter = (0, i), bits = out0 ^ out1)  [verified R2: absmax 1.95e-3]
//   k = (1 - u^(1/b))^(1/a); z = clip(1.2*k - 0.1, 0, 1)
//
// R7 = R5 structure (16-row tiles, merge-tree reduce, per-lane epilogue;
// 43.6us, 6.16 TB/s) + NON-TEMPORAL x loads. R6's compile fix: the builtin
// requires a clang ext_vector_type pointer, not HIP's float4 struct.

typedef float floatx4 __attribute__((ext_vector_type(4)));

__device__ __forceinline__ uint32_t rotl32(uint32_t v, uint32_t r) {
    return (v << r) | (v >> (32u - r));
}

// threefry2x32-20 with key pair (0, 42) == jax.random.key(42)
__device__ __forceinline__ void threefry2x32_k042(uint32_t& x0, uint32_t& x1) {
    const uint32_t ks1 = 42u;
    const uint32_t ks2 = 0x1BD11BDAu ^ 42u;
    x1 += ks1;                                 // x0 += ks0 (=0) elided
#define TFR(r) { x0 += x1; x1 = rotl32(x1, (r)); x1 ^= x0; }
    TFR(13u) TFR(15u) TFR(26u) TFR(6u)
    x0 += ks1; x1 += ks2 + 1u;
    TFR(17u) TFR(29u) TFR(16u) TFR(24u)
    x0 += ks2; x1 += 2u;
    TFR(13u) TFR(15u) TFR(26u) TFR(6u)
    x1 += ks1 + 3u;
    TFR(17u) TFR(29u) TFR(16u) TFR(24u)
    x0 += ks1; x1 += ks2 + 4u;
    TFR(13u) TFR(15u) TFR(26u) TFR(6u)
    x0 += ks2; x1 += 5u;
#undef TFR
}

__device__ __forceinline__ float softplus_f(float v) {
    return fmaxf(v, 0.0f) + log1pf(expf(-fabsf(v)));
}

// merge two lane-distributed partial sums: after this, lanes with
// (lane & m) == 0 hold the u-sum over the lane pair, others the v-sum.
__device__ __forceinline__ float merge_red(float u, float v, int m, int lane) {
    const float s = (lane & m) ? u : v;        // send partner what IT keeps
    const float r = __shfl_xor(s, m, 64);
    return ((lane & m) ? v : u) + r;
}

__device__ __forceinline__ float dot8(const floatx4& v0, const floatx4& v1,
                                      const floatx4& w0, const floatx4& w1) {
    float p = v0.x * w0.x;
    p = fmaf(v0.y, w0.y, p);
    p = fmaf(v0.z, w0.z, p);
    p = fmaf(v0.w, w0.w, p);
    p = fmaf(v1.x, w1.x, p);
    p = fmaf(v1.y, w1.y, p);
    p = fmaf(v1.z, w1.z, p);
    p = fmaf(v1.w, w1.w, p);
    return p;
}

// non-temporal 16B load (x is streamed once; don't allocate in cache)
__device__ __forceinline__ floatx4 ldnt4(const float* p) {
    return __builtin_nontemporal_load(reinterpret_cast<const floatx4*>(p));
}

// plain cached 16B load for reused weight data
__device__ __forceinline__ floatx4 ld4(const float* p) {
    return *reinterpret_cast<const floatx4*>(p);
}

__global__ __launch_bounds__(256) void kuma_mask_kernel(
    const float* __restrict__ x,
    const float* __restrict__ Wa, const float* __restrict__ ba,
    const float* __restrict__ Wb, const float* __restrict__ bb,
    float* __restrict__ out, int nrows)
{
    const int lane = threadIdx.x & 63;
    const int wid  = (int)((blockIdx.x * blockDim.x + threadIdx.x) >> 6);
    const int nw   = (int)((gridDim.x * blockDim.x) >> 6);

    // Per-lane weight fragments (4 KiB total, reused -> cached load)
    const floatx4 wa0 = ld4(Wa + 4 * lane);
    const floatx4 wa1 = ld4(Wa + 256 + 4 * lane);
    const floatx4 wb0 = ld4(Wb + 4 * lane);
    const floatx4 wb1 = ld4(Wb + 256 + 4 * lane);
    const float ba_s = ba[0];
    const float bb_s = bb[0];

    const int ntiles = nrows >> 4;             // 16 rows per tile

    for (int tile = wid; tile < ntiles; tile += nw) {
        const int rowbase = tile << 4;

        // Per-quad (4 rows): dots + merge levels 1,2 -> A[g], B[g];
        // lane bits[1:0] = row-within-quad after these levels.
        float A[4], B[4];
        #pragma unroll
        for (int g = 0; g < 4; ++g) {
            const float* xr = x + (size_t)(rowbase + 4 * g) * 512 + 4 * lane;
            const floatx4 v00 = ldnt4(xr);
            const floatx4 v01 = ldnt4(xr + 256);
            const floatx4 v10 = ldnt4(xr + 512);
            const floatx4 v11 = ldnt4(xr + 768);
            const floatx4 v20 = ldnt4(xr + 1024);
            const floatx4 v21 = ldnt4(xr + 1280);
            const floatx4 v30 = ldnt4(xr + 1536);
            const floatx4 v31 = ldnt4(xr + 1792);

            const float pa0 = dot8(v00, v01, wa0, wa1);
            const float pb0 = dot8(v00, v01, wb0, wb1);
            const float pa1 = dot8(v10, v11, wa0, wa1);
            const float pb1 = dot8(v10, v11, wb0, wb1);
            const float pa2 = dot8(v20, v21, wa0, wa1);
            const float pb2 = dot8(v20, v21, wb0, wb1);
            const float pa3 = dot8(v30, v31, wa0, wa1);
            const float pb3 = dot8(v30, v31, wb0, wb1);

            const float a01 = merge_red(pa0, pa1, 1, lane);
            const float a23 = merge_red(pa2, pa3, 1, lane);
            const float b01 = merge_red(pb0, pb1, 1, lane);
            const float b23 = merge_red(pb2, pb3, 1, lane);
            A[g] = merge_red(a01, a23, 2, lane);   // lane bit1 = row bit1
            B[g] = merge_red(b01, b23, 2, lane);
        }

        // Level mask4: lane bit2 = quad bit0
        const float A40 = merge_red(A[0], A[1], 4, lane);
        const float A41 = merge_red(A[2], A[3], 4, lane);
        const float B40 = merge_red(B[0], B[1], 4, lane);
        const float B41 = merge_red(B[2], B[3], 4, lane);
        // Level mask8: lane bit3 = quad bit1 -> row = lane & 15
        const float A16 = merge_red(A40, A41, 8, lane);
        const float B16 = merge_red(B40, B41, 8, lane);
        // Level mask16: lane bit4 = param (0 = a, 1 = b)
        const float fin0 = merge_red(A16, B16, 16, lane);
        // Complete the 64-lane sum across lane bit5 (same value both sides)
        const float fin = fin0 + __shfl_xor(fin0, 32, 64);
        // Pair a/b into every lane
        const float oth = __shfl_xor(fin, 16, 64);
        const float spa = (lane & 16) ? oth : fin;   // pa(rowbase + (lane&15))
        const float spb = (lane & 16) ? fin : oth;   // pb(rowbase + (lane&15))

        // ---- Epilogue, once per tile; lane l handles row rowbase+(l&15) ----
        const float a = softplus_f(spa + ba_s);
        const float b = softplus_f(spb + bb_s);

        uint32_t t0 = 0u;
        uint32_t t1 = (uint32_t)(rowbase + (lane & 15));
        threefry2x32_k042(t0, t1);
        const uint32_t bits = t0 ^ t1;
        const float f = __uint_as_float((bits >> 9) | 0x3f800000u) - 1.0f;
        const float u = fmaxf(f, 1.17549435e-38f);

        const float p     = expf(logf(u) / b);       // u^(1/b) in (0,1]
        const float one_m = 1.0f - p;
        const float k     = expf(logf(one_m) / a);   // log(0)=-inf -> k=0
        const float z = fminf(fmaxf(fmaf(k, 1.2f, -0.1f), 0.0f), 1.0f);

        if (lane < 16) out[rowbase + lane] = z;
    }
}

extern "C" void kernel_launch(void* const* d_in, const int* in_sizes, int n_in,
                              void* d_out, int out_size, void* d_ws, size_t ws_size,
                              hipStream_t stream) {
    const float* x  = (const float*)d_in[0];
    const float* Wa = (const float*)d_in[1];
    const float* ba = (const float*)d_in[2];
    const float* Wb = (const float*)d_in[3];
    const float* bb = (const float*)d_in[4];
    float* out = (float*)d_out;

    const int nrows = in_sizes[0] / 512;   // 131072

    // 8192 tiles of 16 rows; 2048 blocks x 256 thr = 8192 waves, 1 tile each
    const int block = 256;
    const int grid  = 2048;
    kuma_mask_kernel<<<grid, block, 0, stream>>>(x, Wa, ba, Wb, bb, out, nrows);
}

// Round 8
// 43.422 us; speedup vs baseline: 1.0312x; 1.0312x over previous
//
#include <hip/hip_runtime.h>
#include <stdint.h>

// KumaMask: z = clip(Kumaraswamy-rsample stretch, 0, 1)
//   a = softplus(x·Wa + ba); b = softplus(x·Wb + bb)
//   u = jax.random.uniform(key(42)) — threefry2x32 PARTITIONABLE stream
//     (counter = (0, i), bits = out0 ^ out1)  [verified R2: absmax 1.95e-3]
//   k = (1 - u^(1/b))^(1/a); z = clip(1.2*k - 0.1, 0, 1)
//
// R8 = R5 exactly (best measured: 43.62us = 6.16 TB/s = 98% of the m13
// float4-read ceiling). R7's non-temporal-load experiment REGRESSED 2.7%
// (43.62 -> 44.78us): nt bypasses the cache path that merges per-lane 16B
// streams into full HBM bursts. Reverted. Structure: 16-row tiles/wave,
// coalesced float4 row loads, 31-merge tree reduction (row = lane&15,
// param = lane bit4), per-lane epilogue once per tile, 8192 waves.

__device__ __forceinline__ uint32_t rotl32(uint32_t v, uint32_t r) {
    return (v << r) | (v >> (32u - r));
}

// threefry2x32-20 with key pair (0, 42) == jax.random.key(42)
__device__ __forceinline__ void threefry2x32_k042(uint32_t& x0, uint32_t& x1) {
    const uint32_t ks1 = 42u;
    const uint32_t ks2 = 0x1BD11BDAu ^ 42u;
    x1 += ks1;                                 // x0 += ks0 (=0) elided
#define TFR(r) { x0 += x1; x1 = rotl32(x1, (r)); x1 ^= x0; }
    TFR(13u) TFR(15u) TFR(26u) TFR(6u)
    x0 += ks1; x1 += ks2 + 1u;
    TFR(17u) TFR(29u) TFR(16u) TFR(24u)
    x0 += ks2; x1 += 2u;
    TFR(13u) TFR(15u) TFR(26u) TFR(6u)
    x1 += ks1 + 3u;
    TFR(17u) TFR(29u) TFR(16u) TFR(24u)
    x0 += ks1; x1 += ks2 + 4u;
    TFR(13u) TFR(15u) TFR(26u) TFR(6u)
    x0 += ks2; x1 += 5u;
#undef TFR
}

__device__ __forceinline__ float softplus_f(float v) {
    return fmaxf(v, 0.0f) + log1pf(expf(-fabsf(v)));
}

// merge two lane-distributed partial sums: after this, lanes with
// (lane & m) == 0 hold the u-sum over the lane pair, others the v-sum.
__device__ __forceinline__ float merge_red(float u, float v, int m, int lane) {
    const float s = (lane & m) ? u : v;        // send partner what IT keeps
    const float r = __shfl_xor(s, m, 64);
    return ((lane & m) ? v : u) + r;
}

__device__ __forceinline__ float dot8(const float4& v0, const float4& v1,
                                      const float4& w0, const float4& w1) {
    float p = v0.x * w0.x;
    p = fmaf(v0.y, w0.y, p);
    p = fmaf(v0.z, w0.z, p);
    p = fmaf(v0.w, w0.w, p);
    p = fmaf(v1.x, w1.x, p);
    p = fmaf(v1.y, w1.y, p);
    p = fmaf(v1.z, w1.z, p);
    p = fmaf(v1.w, w1.w, p);
    return p;
}

__global__ __launch_bounds__(256) void kuma_mask_kernel(
    const float* __restrict__ x,
    const float* __restrict__ Wa, const float* __restrict__ ba,
    const float* __restrict__ Wb, const float* __restrict__ bb,
    float* __restrict__ out, int nrows)
{
    const int lane = threadIdx.x & 63;
    const int wid  = (int)((blockIdx.x * blockDim.x + threadIdx.x) >> 6);
    const int nw   = (int)((gridDim.x * blockDim.x) >> 6);

    // Per-lane weight fragments (4 KiB total, L2-resident)
    const float4 wa0 = *reinterpret_cast<const float4*>(Wa + 4 * lane);
    const float4 wa1 = *reinterpret_cast<const float4*>(Wa + 256 + 4 * lane);
    const float4 wb0 = *reinterpret_cast<const float4*>(Wb + 4 * lane);
    const float4 wb1 = *reinterpret_cast<const float4*>(Wb + 256 + 4 * lane);
    const float ba_s = ba[0];
    const float bb_s = bb[0];

    const int ntiles = nrows >> 4;             // 16 rows per tile

    for (int tile = wid; tile < ntiles; tile += nw) {
        const int rowbase = tile << 4;

        // Per-quad (4 rows): dots + merge levels 1,2 -> A[g], B[g];
        // lane bits[1:0] = row-within-quad after these levels.
        float A[4], B[4];
        #pragma unroll
        for (int g = 0; g < 4; ++g) {
            const float* xr = x + (size_t)(rowbase + 4 * g) * 512 + 4 * lane;
            const float4 v00 = *reinterpret_cast<const float4*>(xr);
            const float4 v01 = *reinterpret_cast<const float4*>(xr + 256);
            const float4 v10 = *reinterpret_cast<const float4*>(xr + 512);
            const float4 v11 = *reinterpret_cast<const float4*>(xr + 768);
            const float4 v20 = *reinterpret_cast<const float4*>(xr + 1024);
            const float4 v21 = *reinterpret_cast<const float4*>(xr + 1280);
            const float4 v30 = *reinterpret_cast<const float4*>(xr + 1536);
            const float4 v31 = *reinterpret_cast<const float4*>(xr + 1792);

            const float pa0 = dot8(v00, v01, wa0, wa1);
            const float pb0 = dot8(v00, v01, wb0, wb1);
            const float pa1 = dot8(v10, v11, wa0, wa1);
            const float pb1 = dot8(v10, v11, wb0, wb1);
            const float pa2 = dot8(v20, v21, wa0, wa1);
            const float pb2 = dot8(v20, v21, wb0, wb1);
            const float pa3 = dot8(v30, v31, wa0, wa1);
            const float pb3 = dot8(v30, v31, wb0, wb1);

            const float a01 = merge_red(pa0, pa1, 1, lane);
            const float a23 = merge_red(pa2, pa3, 1, lane);
            const float b01 = merge_red(pb0, pb1, 1, lane);
            const float b23 = merge_red(pb2, pb3, 1, lane);
            A[g] = merge_red(a01, a23, 2, lane);   // lane bit1 = row bit1
            B[g] = merge_red(b01, b23, 2, lane);
        }

        // Level mask4: lane bit2 = quad bit0
        const float A40 = merge_red(A[0], A[1], 4, lane);
        const float A41 = merge_red(A[2], A[3], 4, lane);
        const float B40 = merge_red(B[0], B[1], 4, lane);
        const float B41 = merge_red(B[2], B[3], 4, lane);
        // Level mask8: lane bit3 = quad bit1 -> row = lane & 15
        const float A16 = merge_red(A40, A41, 8, lane);
        const float B16 = merge_red(B40, B41, 8, lane);
        // Level mask16: lane bit4 = param (0 = a, 1 = b)
        const float fin0 = merge_red(A16, B16, 16, lane);
        // Complete the 64-lane sum across lane bit5 (same value both sides)
        const float fin = fin0 + __shfl_xor(fin0, 32, 64);
        // Pair a/b into every lane
        const float oth = __shfl_xor(fin, 16, 64);
        const float spa = (lane & 16) ? oth : fin;   // pa(rowbase + (lane&15))
        const float spb = (lane & 16) ? fin : oth;   // pb(rowbase + (lane&15))

        // ---- Epilogue, once per tile; lane l handles row rowbase+(l&15) ----
        const float a = softplus_f(spa + ba_s);
        const float b = softplus_f(spb + bb_s);

        uint32_t t0 = 0u;
        uint32_t t1 = (uint32_t)(rowbase + (lane & 15));
        threefry2x32_k042(t0, t1);
        const uint32_t bits = t0 ^ t1;
        const float f = __uint_as_float((bits >> 9) | 0x3f800000u) - 1.0f;
        const float u = fmaxf(f, 1.17549435e-38f);

        const float p     = expf(logf(u) / b);       // u^(1/b) in (0,1]
        const float one_m = 1.0f - p;
        const float k     = expf(logf(one_m) / a);   // log(0)=-inf -> k=0
        const float z = fminf(fmaxf(fmaf(k, 1.2f, -0.1f), 0.0f), 1.0f);

        if (lane < 16) out[rowbase + lane] = z;
    }
}

extern "C" void kernel_launch(void* const* d_in, const int* in_sizes, int n_in,
                              void* d_out, int out_size, void* d_ws, size_t ws_size,
                              hipStream_t stream) {
    const float* x  = (const float*)d_in[0];
    const float* Wa = (const float*)d_in[1];
    const float* ba = (const float*)d_in[2];
    const float* Wb = (const float*)d_in[3];
    const float* bb = (const float*)d_in[4];
    float* out = (float*)d_out;

    const int nrows = in_sizes[0] / 512;   // 131072

    // 8192 tiles of 16 rows; 2048 blocks x 256 thr = 8192 waves, 1 tile each
    const int block = 256;
    const int grid  = 2048;
    kuma_mask_kernel<<<grid, block, 0, stream>>>(x, Wa, ba, Wb, bb, out, nrows);
}